// Round 1
// baseline (102.649 us; speedup 1.0000x reference)
//
#include <hip/hip_runtime.h>
#include <cstddef>

#define BB 4
#define NN 256
#define HH 256
#define BN_EPS 1e-5f
#define ETA_EPS 1e-20f

// ---------------------------------------------------------------------------
// Kernel 1: projections  x_left = nodes @ W1^T, x_w2 = nodes @ W2^T
// grid = 128 blocks: [0,64) -> W1, [64,128) -> W2; each block does 16 rows.
// ---------------------------------------------------------------------------
__global__ __launch_bounds__(256) void proj_kernel(
    const float* __restrict__ nodes, const float* __restrict__ W1,
    const float* __restrict__ W2, float* __restrict__ xleft,
    float* __restrict__ xw2)
{
    const int which = blockIdx.x >> 6;   // 0 -> W1/xleft, 1 -> W2/xw2
    const int rb    = blockIdx.x & 63;   // 16-row block index (64 * 16 = 1024)
    const int t     = threadIdx.x;
    const float* __restrict__ W  = which ? W2  : W1;
    float* __restrict__ out      = which ? xw2 : xleft;

    __shared__ float xs[16][HH];
    const int base = rb * 16 * HH;
    for (int idx = t; idx < 16 * HH; idx += 256)
        xs[idx >> 8][idx & 255] = nodes[base + idx];
    __syncthreads();

    float acc[16];
#pragma unroll
    for (int r = 0; r < 16; ++r) acc[r] = 0.f;

    const int o = t;  // output channel
    const float4* __restrict__ Wrow = reinterpret_cast<const float4*>(W + o * HH);
    for (int h4 = 0; h4 < HH / 4; ++h4) {
        float4 w = Wrow[h4];
#pragma unroll
        for (int r = 0; r < 16; ++r) {
            float4 x = *reinterpret_cast<const float4*>(&xs[r][h4 * 4]);
            acc[r] += x.x * w.x + x.y * w.y + x.z * w.z + x.w * w.w;
        }
    }
#pragma unroll
    for (int r = 0; r < 16; ++r)
        out[(rb * 16 + r) * HH + o] = acc[r];
}

// ---------------------------------------------------------------------------
// Kernel 2: the memory-bound workhorse. One block per (b,i).
//   S0[h] = sum_j sigmoid(edges[b,i,j,h])
//   S1[h] = sum_j sigmoid(edges[b,i,j,h]) * x_w2[b,j,h]
//   equ[b,i,h] = x_left[b,i,h] + S1/(S0 + ETA_EPS)
// 256 threads: jg = t>>6 (j stride group), hq = t&63 (float4 channel quad).
// ---------------------------------------------------------------------------
__global__ __launch_bounds__(256) void edge_kernel(
    const float* __restrict__ edges, const float* __restrict__ xw2,
    const float* __restrict__ xleft, float* __restrict__ equ)
{
    const int bi = blockIdx.x;       // b*N + i
    const int b  = bi >> 8;
    const int t  = threadIdx.x;
    const int jg = t >> 6;
    const int hq = t & 63;

    const float4* __restrict__ erow =
        reinterpret_cast<const float4*>(edges) + (size_t)bi * NN * (HH / 4);
    const float4* __restrict__ xwrow =
        reinterpret_cast<const float4*>(xw2) + (size_t)b * NN * (HH / 4);

    float s0[4] = {0.f, 0.f, 0.f, 0.f};
    float s1[4] = {0.f, 0.f, 0.f, 0.f};

    for (int j = jg; j < NN; j += 4) {
        float4 e  = erow[j * (HH / 4) + hq];
        float4 xw = xwrow[j * (HH / 4) + hq];
        float sg;
        sg = 1.f / (1.f + __expf(-e.x)); s0[0] += sg; s1[0] += sg * xw.x;
        sg = 1.f / (1.f + __expf(-e.y)); s0[1] += sg; s1[1] += sg * xw.y;
        sg = 1.f / (1.f + __expf(-e.z)); s0[2] += sg; s1[2] += sg * xw.z;
        sg = 1.f / (1.f + __expf(-e.w)); s0[3] += sg; s1[3] += sg * xw.w;
    }

    __shared__ float red0[4][64][4];
    __shared__ float red1[4][64][4];
#pragma unroll
    for (int k = 0; k < 4; ++k) { red0[jg][hq][k] = s0[k]; red1[jg][hq][k] = s1[k]; }
    __syncthreads();

    if (t < 64) {
        float4 xl = reinterpret_cast<const float4*>(xleft)[bi * (HH / 4) + t];
        float res[4];
#pragma unroll
        for (int k = 0; k < 4; ++k) {
            float S0 = red0[0][t][k] + red0[1][t][k] + red0[2][t][k] + red0[3][t][k];
            float S1 = red1[0][t][k] + red1[1][t][k] + red1[2][t][k] + red1[3][t][k];
            res[k] = S1 / (S0 + ETA_EPS);
        }
        float4 o;
        o.x = xl.x + res[0];
        o.y = xl.y + res[1];
        o.z = xl.z + res[2];
        o.w = xl.w + res[3];
        reinterpret_cast<float4*>(equ)[bi * (HH / 4) + t] = o;
    }
}

// ---------------------------------------------------------------------------
// Kernel 3: BN batch stats over (B,N) = 1024 rows per channel.
// grid = 4 blocks x 1024 threads; block bq handles channels [bq*64, bq*64+64).
// Deterministic fixed-order reduction. Emits fused scale/shift.
// ---------------------------------------------------------------------------
__global__ __launch_bounds__(1024) void stats_kernel(
    const float* __restrict__ equ, const float* __restrict__ gamma,
    const float* __restrict__ beta, float* __restrict__ scale,
    float* __restrict__ shift)
{
    const int lane = threadIdx.x & 63;
    const int rg   = threadIdx.x >> 6;    // 0..15
    const int c    = (blockIdx.x << 6) | lane;

    float s = 0.f, q = 0.f;
    for (int r = rg; r < BB * NN; r += 16) {
        float v = equ[r * HH + c];
        s += v;
        q += v * v;
    }

    __shared__ float sp[16][64];
    __shared__ float qp[16][64];
    sp[rg][lane] = s;
    qp[rg][lane] = q;
    __syncthreads();

    if (threadIdx.x < 64) {
        float S = 0.f, Q = 0.f;
#pragma unroll
        for (int g = 0; g < 16; ++g) { S += sp[g][threadIdx.x]; Q += qp[g][threadIdx.x]; }
        const float inv_n = 1.f / (float)(BB * NN);
        float mean = S * inv_n;
        float var  = Q * inv_n - mean * mean;
        float rstd = rsqrtf(var + BN_EPS);
        int cc = (blockIdx.x << 6) | threadIdx.x;
        float g  = gamma[cc];
        float bt = beta[cc];
        scale[cc] = rstd * g;
        shift[cc] = bt - mean * rstd * g;
    }
}

// ---------------------------------------------------------------------------
// Kernel 4: apply normalization. float4 elementwise.
// grid = 256 blocks x 256 threads over 65536 float4 elements.
// ---------------------------------------------------------------------------
__global__ __launch_bounds__(256) void norm_kernel(
    const float* __restrict__ equ, const float* __restrict__ scale,
    const float* __restrict__ shift, float* __restrict__ out)
{
    const int idx = blockIdx.x * 256 + threadIdx.x;   // float4 index
    float4 e  = reinterpret_cast<const float4*>(equ)[idx];
    const int c4 = idx & 63;                          // channel quad
    float4 sc = reinterpret_cast<const float4*>(scale)[c4];
    float4 sh = reinterpret_cast<const float4*>(shift)[c4];
    float4 o;
    o.x = e.x * sc.x + sh.x;
    o.y = e.y * sc.y + sh.y;
    o.z = e.z * sc.z + sh.z;
    o.w = e.w * sc.w + sh.w;
    reinterpret_cast<float4*>(out)[idx] = o;
}

// ---------------------------------------------------------------------------
extern "C" void kernel_launch(void* const* d_in, const int* in_sizes, int n_in,
                              void* d_out, int out_size, void* d_ws, size_t ws_size,
                              hipStream_t stream) {
    (void)in_sizes; (void)n_in; (void)out_size; (void)ws_size;

    const float* nodes = (const float*)d_in[0];
    const float* edges = (const float*)d_in[1];
    const float* W1    = (const float*)d_in[2];
    const float* W2    = (const float*)d_in[3];
    const float* gamma = (const float*)d_in[4];
    const float* beta  = (const float*)d_in[5];
    float* out = (float*)d_out;

    const int nBN_H = BB * NN * HH;  // 262144
    float* ws    = (float*)d_ws;
    float* xleft = ws;
    float* xw2   = ws + nBN_H;
    float* equ   = ws + 2 * nBN_H;
    float* scale = ws + 3 * nBN_H;
    float* shift = ws + 3 * nBN_H + HH;

    proj_kernel<<<128, 256, 0, stream>>>(nodes, W1, W2, xleft, xw2);
    edge_kernel<<<BB * NN, 256, 0, stream>>>(edges, xw2, xleft, equ);
    stats_kernel<<<4, 1024, 0, stream>>>(equ, gamma, beta, scale, shift);
    norm_kernel<<<256, 256, 0, stream>>>(equ, scale, shift, out);
}

// Round 2
// 93.288 us; speedup vs baseline: 1.1003x; 1.1003x over previous
//
#include <hip/hip_runtime.h>
#include <cstddef>

#define BB 4
#define NN 256
#define HH 256
#define BN_EPS 1e-5f
#define ETA_EPS 1e-20f

// Fast sigmoid: v_mul + v_exp_f32 + v_add + v_rcp_f32 (no IEEE div sequence).
// v_rcp_f32 is ~1 ulp; absmax threshold is 8.8e-2, so this is trivially safe.
__device__ __forceinline__ float fast_sigmoid(float x) {
    float ex = __expf(-x);                 // v_mul(log2e) + v_exp_f32
    return __builtin_amdgcn_rcpf(1.f + ex); // v_add + v_rcp_f32
}

// ---------------------------------------------------------------------------
// Kernel 1: projections  x_left = nodes @ W1^T, x_w2 = nodes @ W2^T
// grid = 128 blocks: [0,64) -> W1, [64,128) -> W2; each block does 16 rows.
// ---------------------------------------------------------------------------
__global__ __launch_bounds__(256) void proj_kernel(
    const float* __restrict__ nodes, const float* __restrict__ W1,
    const float* __restrict__ W2, float* __restrict__ xleft,
    float* __restrict__ xw2)
{
    const int which = blockIdx.x >> 6;   // 0 -> W1/xleft, 1 -> W2/xw2
    const int rb    = blockIdx.x & 63;   // 16-row block index (64 * 16 = 1024)
    const int t     = threadIdx.x;
    const float* __restrict__ W  = which ? W2  : W1;
    float* __restrict__ out      = which ? xw2 : xleft;

    __shared__ float xs[16][HH];
    const int base = rb * 16 * HH;
    for (int idx = t; idx < 16 * HH; idx += 256)
        xs[idx >> 8][idx & 255] = nodes[base + idx];
    __syncthreads();

    float acc[16];
#pragma unroll
    for (int r = 0; r < 16; ++r) acc[r] = 0.f;

    const int o = t;  // output channel
    const float4* __restrict__ Wrow = reinterpret_cast<const float4*>(W + o * HH);
    for (int h4 = 0; h4 < HH / 4; ++h4) {
        float4 w = Wrow[h4];
#pragma unroll
        for (int r = 0; r < 16; ++r) {
            float4 x = *reinterpret_cast<const float4*>(&xs[r][h4 * 4]);
            acc[r] += x.x * w.x + x.y * w.y + x.z * w.z + x.w * w.w;
        }
    }
#pragma unroll
    for (int r = 0; r < 16; ++r)
        out[(rb * 16 + r) * HH + o] = acc[r];
}

// ---------------------------------------------------------------------------
// Kernel 2: the memory-bound workhorse. One block per (b,i).
//   S0[h] = sum_j sigmoid(edges[b,i,j,h])
//   S1[h] = sum_j sigmoid(edges[b,i,j,h]) * x_w2[b,j,h]
//   equ[b,i,h] = x_left[b,i,h] + S1/(S0 + ETA_EPS)
// 256 threads: jg = t>>6 (j stride group), hq = t&63 (float4 channel quad).
// ---------------------------------------------------------------------------
__global__ __launch_bounds__(256) void edge_kernel(
    const float* __restrict__ edges, const float* __restrict__ xw2,
    const float* __restrict__ xleft, float* __restrict__ equ)
{
    const int bi = blockIdx.x;       // b*N + i
    const int b  = bi >> 8;
    const int t  = threadIdx.x;
    const int jg = t >> 6;
    const int hq = t & 63;

    const float4* __restrict__ erow =
        reinterpret_cast<const float4*>(edges) + (size_t)bi * NN * (HH / 4);
    const float4* __restrict__ xwrow =
        reinterpret_cast<const float4*>(xw2) + (size_t)b * NN * (HH / 4);

    float s0[4] = {0.f, 0.f, 0.f, 0.f};
    float s1[4] = {0.f, 0.f, 0.f, 0.f};

#pragma unroll 4
    for (int j = jg; j < NN; j += 4) {
        float4 e  = erow[j * (HH / 4) + hq];
        float4 xw = xwrow[j * (HH / 4) + hq];
        float sg;
        sg = fast_sigmoid(e.x); s0[0] += sg; s1[0] += sg * xw.x;
        sg = fast_sigmoid(e.y); s0[1] += sg; s1[1] += sg * xw.y;
        sg = fast_sigmoid(e.z); s0[2] += sg; s1[2] += sg * xw.z;
        sg = fast_sigmoid(e.w); s0[3] += sg; s1[3] += sg * xw.w;
    }

    __shared__ float red0[4][64][4];
    __shared__ float red1[4][64][4];
#pragma unroll
    for (int k = 0; k < 4; ++k) { red0[jg][hq][k] = s0[k]; red1[jg][hq][k] = s1[k]; }
    __syncthreads();

    if (t < 64) {
        float4 xl = reinterpret_cast<const float4*>(xleft)[bi * (HH / 4) + t];
        float res[4];
#pragma unroll
        for (int k = 0; k < 4; ++k) {
            float S0 = red0[0][t][k] + red0[1][t][k] + red0[2][t][k] + red0[3][t][k];
            float S1 = red1[0][t][k] + red1[1][t][k] + red1[2][t][k] + red1[3][t][k];
            res[k] = S1 / (S0 + ETA_EPS);   // 64 lanes once per block: keep IEEE
        }
        float4 o;
        o.x = xl.x + res[0];
        o.y = xl.y + res[1];
        o.z = xl.z + res[2];
        o.w = xl.w + res[3];
        reinterpret_cast<float4*>(equ)[bi * (HH / 4) + t] = o;
    }
}

// ---------------------------------------------------------------------------
// Kernel 3: BN batch stats over (B,N) = 1024 rows per channel.
// grid = 4 blocks x 1024 threads; block bq handles channels [bq*64, bq*64+64).
// Deterministic fixed-order reduction. Emits fused scale/shift.
// ---------------------------------------------------------------------------
__global__ __launch_bounds__(1024) void stats_kernel(
    const float* __restrict__ equ, const float* __restrict__ gamma,
    const float* __restrict__ beta, float* __restrict__ scale,
    float* __restrict__ shift)
{
    const int lane = threadIdx.x & 63;
    const int rg   = threadIdx.x >> 6;    // 0..15
    const int c    = (blockIdx.x << 6) | lane;

    float s = 0.f, q = 0.f;
    for (int r = rg; r < BB * NN; r += 16) {
        float v = equ[r * HH + c];
        s += v;
        q += v * v;
    }

    __shared__ float sp[16][64];
    __shared__ float qp[16][64];
    sp[rg][lane] = s;
    qp[rg][lane] = q;
    __syncthreads();

    if (threadIdx.x < 64) {
        float S = 0.f, Q = 0.f;
#pragma unroll
        for (int g = 0; g < 16; ++g) { S += sp[g][threadIdx.x]; Q += qp[g][threadIdx.x]; }
        const float inv_n = 1.f / (float)(BB * NN);
        float mean = S * inv_n;
        float var  = Q * inv_n - mean * mean;
        float rstd = rsqrtf(var + BN_EPS);
        int cc = (blockIdx.x << 6) | threadIdx.x;
        float g  = gamma[cc];
        float bt = beta[cc];
        scale[cc] = rstd * g;
        shift[cc] = bt - mean * rstd * g;
    }
}

// ---------------------------------------------------------------------------
// Kernel 4: apply normalization. float4 elementwise.
// grid = 256 blocks x 256 threads over 65536 float4 elements.
// ---------------------------------------------------------------------------
__global__ __launch_bounds__(256) void norm_kernel(
    const float* __restrict__ equ, const float* __restrict__ scale,
    const float* __restrict__ shift, float* __restrict__ out)
{
    const int idx = blockIdx.x * 256 + threadIdx.x;   // float4 index
    float4 e  = reinterpret_cast<const float4*>(equ)[idx];
    const int c4 = idx & 63;                          // channel quad
    float4 sc = reinterpret_cast<const float4*>(scale)[c4];
    float4 sh = reinterpret_cast<const float4*>(shift)[c4];
    float4 o;
    o.x = e.x * sc.x + sh.x;
    o.y = e.y * sc.y + sh.y;
    o.z = e.z * sc.z + sh.z;
    o.w = e.w * sc.w + sh.w;
    reinterpret_cast<float4*>(out)[idx] = o;
}

// ---------------------------------------------------------------------------
extern "C" void kernel_launch(void* const* d_in, const int* in_sizes, int n_in,
                              void* d_out, int out_size, void* d_ws, size_t ws_size,
                              hipStream_t stream) {
    (void)in_sizes; (void)n_in; (void)out_size; (void)ws_size;

    const float* nodes = (const float*)d_in[0];
    const float* edges = (const float*)d_in[1];
    const float* W1    = (const float*)d_in[2];
    const float* W2    = (const float*)d_in[3];
    const float* gamma = (const float*)d_in[4];
    const float* beta  = (const float*)d_in[5];
    float* out = (float*)d_out;

    const int nBN_H = BB * NN * HH;  // 262144
    float* ws    = (float*)d_ws;
    float* xleft = ws;
    float* xw2   = ws + nBN_H;
    float* equ   = ws + 2 * nBN_H;
    float* scale = ws + 3 * nBN_H;
    float* shift = ws + 3 * nBN_H + HH;

    proj_kernel<<<128, 256, 0, stream>>>(nodes, W1, W2, xleft, xw2);
    edge_kernel<<<BB * NN, 256, 0, stream>>>(edges, xw2, xleft, equ);
    stats_kernel<<<4, 1024, 0, stream>>>(equ, gamma, beta, scale, shift);
    norm_kernel<<<256, 256, 0, stream>>>(equ, scale, shift, out);
}

// Round 3
// 88.239 us; speedup vs baseline: 1.1633x; 1.0572x over previous
//
#include <hip/hip_runtime.h>
#include <cstddef>

#define BB 4
#define NN 256
#define HH 256
#define BN_EPS 1e-5f
#define ETA_EPS 1e-20f

typedef float f4 __attribute__((ext_vector_type(4)));

// Fast sigmoid: v_mul + v_exp_f32 + v_add + v_rcp_f32 (no IEEE div sequence).
__device__ __forceinline__ float fast_sigmoid(float x) {
    float ex = __expf(-x);
    return __builtin_amdgcn_rcpf(1.f + ex);
}

// ---------------------------------------------------------------------------
// Kernel 1: projections  x_left = nodes @ W1^T, x_w2 = nodes @ W2^T
// grid = 512 blocks: [0,256) -> W1, [256,512) -> W2; each block does 4 rows.
// 2 blocks/CU -> full chip. W rows L1/L2-cached (16B/lane thread-private
// streams, 16 KB live set fits L1).
// ---------------------------------------------------------------------------
__global__ __launch_bounds__(256) void proj_kernel(
    const float* __restrict__ nodes, const float* __restrict__ W1,
    const float* __restrict__ W2, float* __restrict__ xleft,
    float* __restrict__ xw2)
{
    const int which = blockIdx.x >> 8;   // 0 -> W1/xleft, 1 -> W2/xw2
    const int rb    = blockIdx.x & 255;  // 4-row group (256 * 4 = 1024 rows)
    const int t     = threadIdx.x;
    const float* __restrict__ W  = which ? W2  : W1;
    float* __restrict__ out      = which ? xw2 : xleft;

    __shared__ f4 xs[4][64];
    const f4* __restrict__ nodes4 = reinterpret_cast<const f4*>(nodes) + rb * 256;
    xs[t >> 6][t & 63] = nodes4[t];      // 256 threads cover 4 rows x 64 quads
    __syncthreads();

    float acc[4] = {0.f, 0.f, 0.f, 0.f};
    const f4* __restrict__ Wrow = reinterpret_cast<const f4*>(W + t * HH);
    for (int h4 = 0; h4 < HH / 4; ++h4) {
        f4 w = Wrow[h4];
#pragma unroll
        for (int r = 0; r < 4; ++r) {
            f4 x = xs[r][h4];
            acc[r] += x[0] * w[0] + x[1] * w[1] + x[2] * w[2] + x[3] * w[3];
        }
    }
#pragma unroll
    for (int r = 0; r < 4; ++r)
        out[(rb * 4 + r) * HH + t] = acc[r];
}

// ---------------------------------------------------------------------------
// Kernel 2: memory-bound workhorse. One block of 1024 threads per (b,i).
//   S0[h] = sum_j sigmoid(edges[b,i,j,h])
//   S1[h] = sum_j sigmoid(edges[b,i,j,h]) * x_w2[b,j,h]
//   equ[b,i,h] = x_left[b,i,h] + S1/(S0 + ETA_EPS)
// 16 j-groups x 64 channel-quads. 2 blocks/CU resident (32 KB LDS) ->
// 32 waves/CU. edges loaded nontemporal so the 256 MB stream doesn't evict
// xw2 (1 MB, reused by all blocks) from L2.
// ---------------------------------------------------------------------------
__global__ __launch_bounds__(1024) void edge_kernel(
    const float* __restrict__ edges, const float* __restrict__ xw2,
    const float* __restrict__ xleft, float* __restrict__ equ)
{
    const int bi = blockIdx.x;       // b*N + i
    const int b  = bi >> 8;
    const int t  = threadIdx.x;
    const int jg = t >> 6;           // 0..15
    const int hq = t & 63;           // channel quad

    const f4* __restrict__ erow =
        reinterpret_cast<const f4*>(edges) + (size_t)bi * NN * (HH / 4);
    const f4* __restrict__ xwrow =
        reinterpret_cast<const f4*>(xw2) + (size_t)b * NN * (HH / 4);

    float s0[4] = {0.f, 0.f, 0.f, 0.f};
    float s1[4] = {0.f, 0.f, 0.f, 0.f};

#pragma unroll 4
    for (int j = jg; j < NN; j += 16) {
        f4 e  = __builtin_nontemporal_load(erow + j * (HH / 4) + hq);
        f4 xw = xwrow[j * (HH / 4) + hq];
#pragma unroll
        for (int k = 0; k < 4; ++k) {
            float sg = fast_sigmoid(e[k]);
            s0[k] += sg;
            s1[k] += sg * xw[k];
        }
    }

    __shared__ float red0[16][64][4];   // 16 KB
    __shared__ float red1[16][64][4];   // 16 KB
#pragma unroll
    for (int k = 0; k < 4; ++k) { red0[jg][hq][k] = s0[k]; red1[jg][hq][k] = s1[k]; }
    __syncthreads();

    if (t < 64) {
        f4 xl = reinterpret_cast<const f4*>(xleft)[bi * (HH / 4) + t];
        f4 o;
#pragma unroll
        for (int k = 0; k < 4; ++k) {
            float S0 = 0.f, S1 = 0.f;
#pragma unroll
            for (int g = 0; g < 16; ++g) { S0 += red0[g][t][k]; S1 += red1[g][t][k]; }
            o[k] = xl[k] + S1 / (S0 + ETA_EPS);
        }
        reinterpret_cast<f4*>(equ)[bi * (HH / 4) + t] = o;
    }
}

// ---------------------------------------------------------------------------
// Kernel 3: BN batch stats. 4 blocks x 1024 threads; block bq handles
// channels [bq*64, bq*64+64) = 16 float4 quads; 64 r-groups, float4 loads.
// Deterministic fixed-order reduction. Emits fused scale/shift.
// ---------------------------------------------------------------------------
__global__ __launch_bounds__(1024) void stats_kernel(
    const float* __restrict__ equ, const float* __restrict__ gamma,
    const float* __restrict__ beta, float* __restrict__ scale,
    float* __restrict__ shift)
{
    const int lane = threadIdx.x & 15;    // quad within block's 16
    const int rg   = threadIdx.x >> 4;    // 0..63
    const int qbase = blockIdx.x * 16;    // first quad of this block

    const f4* __restrict__ equ4 = reinterpret_cast<const f4*>(equ);

    float s[4] = {0.f, 0.f, 0.f, 0.f};
    float q[4] = {0.f, 0.f, 0.f, 0.f};
    for (int r = rg; r < BB * NN; r += 64) {
        f4 v = equ4[r * (HH / 4) + qbase + lane];
#pragma unroll
        for (int k = 0; k < 4; ++k) { s[k] += v[k]; q[k] += v[k] * v[k]; }
    }

    __shared__ float sp[64][16][4];   // 16 KB
    __shared__ float qp[64][16][4];   // 16 KB
#pragma unroll
    for (int k = 0; k < 4; ++k) { sp[rg][lane][k] = s[k]; qp[rg][lane][k] = q[k]; }
    __syncthreads();

    if (threadIdx.x < 64) {
        const int quad = threadIdx.x >> 2;
        const int comp = threadIdx.x & 3;
        float S = 0.f, Q = 0.f;
#pragma unroll
        for (int g = 0; g < 64; ++g) { S += sp[g][quad][comp]; Q += qp[g][quad][comp]; }
        const float inv_n = 1.f / (float)(BB * NN);
        float mean = S * inv_n;
        float var  = Q * inv_n - mean * mean;
        float rstd = rsqrtf(var + BN_EPS);
        int cc = (qbase << 2) | threadIdx.x;
        float g  = gamma[cc];
        float bt = beta[cc];
        scale[cc] = rstd * g;
        shift[cc] = bt - mean * rstd * g;
    }
}

// ---------------------------------------------------------------------------
// Kernel 4: apply normalization. float4 elementwise.
// ---------------------------------------------------------------------------
__global__ __launch_bounds__(256) void norm_kernel(
    const float* __restrict__ equ, const float* __restrict__ scale,
    const float* __restrict__ shift, float* __restrict__ out)
{
    const int idx = blockIdx.x * 256 + threadIdx.x;   // float4 index
    f4 e  = reinterpret_cast<const f4*>(equ)[idx];
    const int c4 = idx & 63;                          // channel quad
    f4 sc = reinterpret_cast<const f4*>(scale)[c4];
    f4 sh = reinterpret_cast<const f4*>(shift)[c4];
    f4 o;
#pragma unroll
    for (int k = 0; k < 4; ++k) o[k] = e[k] * sc[k] + sh[k];
    reinterpret_cast<f4*>(out)[idx] = o;
}

// ---------------------------------------------------------------------------
extern "C" void kernel_launch(void* const* d_in, const int* in_sizes, int n_in,
                              void* d_out, int out_size, void* d_ws, size_t ws_size,
                              hipStream_t stream) {
    (void)in_sizes; (void)n_in; (void)out_size; (void)ws_size;

    const float* nodes = (const float*)d_in[0];
    const float* edges = (const float*)d_in[1];
    const float* W1    = (const float*)d_in[2];
    const float* W2    = (const float*)d_in[3];
    const float* gamma = (const float*)d_in[4];
    const float* beta  = (const float*)d_in[5];
    float* out = (float*)d_out;

    const int nBN_H = BB * NN * HH;  // 262144
    float* ws    = (float*)d_ws;
    float* xleft = ws;
    float* xw2   = ws + nBN_H;
    float* equ   = ws + 2 * nBN_H;
    float* scale = ws + 3 * nBN_H;
    float* shift = ws + 3 * nBN_H + HH;

    proj_kernel<<<512, 256, 0, stream>>>(nodes, W1, W2, xleft, xw2);
    edge_kernel<<<BB * NN, 1024, 0, stream>>>(edges, xw2, xleft, equ);
    stats_kernel<<<4, 1024, 0, stream>>>(equ, gamma, beta, scale, shift);
    norm_kernel<<<256, 256, 0, stream>>>(equ, scale, shift, out);
}

// Round 4
// 84.351 us; speedup vs baseline: 1.2169x; 1.0461x over previous
//
#include <hip/hip_runtime.h>
#include <cstddef>

#define BB 4
#define NN 256
#define HH 256
#define BN_EPS 1e-5f
#define ETA_EPS 1e-20f

typedef float f4 __attribute__((ext_vector_type(4)));

// Fast sigmoid: v_mul + v_exp_f32 + v_add + v_rcp_f32 (no IEEE div sequence).
__device__ __forceinline__ float fast_sigmoid(float x) {
    float ex = __expf(-x);
    return __builtin_amdgcn_rcpf(1.f + ex);
}

// ---------------------------------------------------------------------------
// Kernel 1: projections  x_left = nodes @ W1^T, x_w2 = nodes @ W2^T
// grid = 512 blocks: [0,256) -> W1, [256,512) -> W2; each block does 4 rows.
// ---------------------------------------------------------------------------
__global__ __launch_bounds__(256) void proj_kernel(
    const float* __restrict__ nodes, const float* __restrict__ W1,
    const float* __restrict__ W2, float* __restrict__ xleft,
    float* __restrict__ xw2)
{
    const int which = blockIdx.x >> 8;   // 0 -> W1/xleft, 1 -> W2/xw2
    const int rb    = blockIdx.x & 255;  // 4-row group (256 * 4 = 1024 rows)
    const int t     = threadIdx.x;
    const float* __restrict__ W  = which ? W2  : W1;
    float* __restrict__ out      = which ? xw2 : xleft;

    __shared__ f4 xs[4][64];
    const f4* __restrict__ nodes4 = reinterpret_cast<const f4*>(nodes) + rb * 256;
    xs[t >> 6][t & 63] = nodes4[t];      // 256 threads cover 4 rows x 64 quads
    __syncthreads();

    float acc[4] = {0.f, 0.f, 0.f, 0.f};
    const f4* __restrict__ Wrow = reinterpret_cast<const f4*>(W + t * HH);
    for (int h4 = 0; h4 < HH / 4; ++h4) {
        f4 w = Wrow[h4];
#pragma unroll
        for (int r = 0; r < 4; ++r) {
            f4 x = xs[r][h4];
            acc[r] += x[0] * w[0] + x[1] * w[1] + x[2] * w[2] + x[3] * w[3];
        }
    }
#pragma unroll
    for (int r = 0; r < 4; ++r)
        out[(rb * 4 + r) * HH + t] = acc[r];
}

// ---------------------------------------------------------------------------
// Kernel 2: memory-bound workhorse, i-tiled with xw2 staged in LDS.
// Block = 8 i-rows x 64-channel slice x all j. Grid = 128 i-groups x 4 slices
// = 512 blocks x 1024 threads; 64 KB LDS -> 2 blocks/CU, one full round.
//   S0[h] = sum_j sigmoid(edges[b,i,j,h])
//   S1[h] = sum_j sigmoid(edges[b,i,j,h]) * xw2[b,j,h]
//   equ[b,i,h] = xleft[b,i,h] + S1/(S0 + ETA_EPS)
// xw2 slice (256 j x 64 ch = 64 KB) loaded to LDS ONCE per block: logical
// xw2 global traffic 256 MB -> 32 MB, removing the HBM re-read that R3's
// L2-reliant version paid. Reduction arrays overlay xw_s after the j-loop.
// ---------------------------------------------------------------------------
__global__ __launch_bounds__(1024) void edge_kernel(
    const float* __restrict__ edges, const float* __restrict__ xw2,
    const float* __restrict__ xleft, float* __restrict__ equ)
{
    const int blk = blockIdx.x;
    const int ig  = blk >> 2;          // i-group of 8 rows: 0..127
    const int hs4 = (blk & 3) * 16;    // first f4 quad of 64-ch slice
    const int bi0 = ig * 8;            // first b*N+i (8 | 256, never crosses b)
    const int b   = bi0 >> 8;
    const int t   = threadIdx.x;

    __shared__ f4 xw_s[NN][16];        // 64 KB; overlaid by red0/red1 later

    const f4* __restrict__ xw4 =
        reinterpret_cast<const f4*>(xw2) + (size_t)b * NN * 64;
#pragma unroll
    for (int m = 0; m < 4; ++m) {
        int idx = m * 1024 + t;        // 0..4095
        int j = idx >> 4, q = idx & 15;
        xw_s[j][q] = xw4[j * 64 + hs4 + q];
    }
    __syncthreads();

    const int q  = t & 15;             // channel quad within slice
    const int il = (t >> 4) & 7;       // i within tile
    const int jg = t >> 7;             // 0..7, j stride group

    const f4* __restrict__ erow =
        reinterpret_cast<const f4*>(edges) +
        (size_t)(bi0 + il) * (NN * 64) + hs4 + q;

    float s0[4] = {0.f, 0.f, 0.f, 0.f};
    float s1[4] = {0.f, 0.f, 0.f, 0.f};

#pragma unroll 2
    for (int j = jg; j < NN; j += 8) {
        f4 e  = __builtin_nontemporal_load(erow + j * 64);
        f4 xw = xw_s[j][q];
#pragma unroll
        for (int k = 0; k < 4; ++k) {
            float sg = fast_sigmoid(e[k]);
            s0[k] += sg;
            s1[k] += sg * xw[k];
        }
    }
    __syncthreads();                   // xw_s dead; reuse for reduction

    float* red = reinterpret_cast<float*>(xw_s);
    // red0[jg][il][q][k] = red[(jg*8+il)*64 + q*4+k]; red1 at +4096 floats.
    {
        float* r0 = red + ((jg * 8 + il) * 16 + q) * 4;
        float* r1 = r0 + 4096;
#pragma unroll
        for (int k = 0; k < 4; ++k) { r0[k] = s0[k]; r1[k] = s1[k]; }
    }
    __syncthreads();

    if (t < 512) {
        const int il2 = t >> 6;        // 0..7
        const int ch  = t & 63;        // channel within slice
        float S0 = 0.f, S1 = 0.f;
#pragma unroll
        for (int g = 0; g < 8; ++g) {
            S0 += red[(g * 8 + il2) * 64 + ch];
            S1 += red[(g * 8 + il2) * 64 + ch + 4096];
        }
        const size_t off = (size_t)(bi0 + il2) * HH + hs4 * 4 + ch;
        equ[off] = xleft[off] + S1 / (S0 + ETA_EPS);
    }
}

// ---------------------------------------------------------------------------
// Kernel 3: BN batch stats. 16 blocks x 1024 threads; block handles 16
// channels (4 f4 quads). Fixed-order deterministic reduction, padded LDS.
// ---------------------------------------------------------------------------
__global__ __launch_bounds__(1024) void stats_kernel(
    const float* __restrict__ equ, const float* __restrict__ gamma,
    const float* __restrict__ beta, float* __restrict__ scale,
    float* __restrict__ shift)
{
    const int t     = threadIdx.x;
    const int ql    = t & 3;            // quad within block's 4
    const int rg    = t >> 2;           // 0..255
    const int qbase = blockIdx.x * 4;   // first f4 quad

    const f4* __restrict__ equ4 = reinterpret_cast<const f4*>(equ);

    float s[4] = {0.f, 0.f, 0.f, 0.f};
    float qq[4] = {0.f, 0.f, 0.f, 0.f};
    for (int r = rg; r < BB * NN; r += 256) {   // 4 iters, ascending
        f4 v = equ4[r * 64 + qbase + ql];
#pragma unroll
        for (int k = 0; k < 4; ++k) { s[k] += v[k]; qq[k] += v[k] * v[k]; }
    }

    __shared__ float sp[256][17];
    __shared__ float qp[256][17];
    __shared__ float sp2[16][17];
    __shared__ float qp2[16][17];
#pragma unroll
    for (int k = 0; k < 4; ++k) { sp[rg][ql * 4 + k] = s[k]; qp[rg][ql * 4 + k] = qq[k]; }
    __syncthreads();

    if (t < 256) {
        const int ch = t & 15, seg = t >> 4;
        float S = 0.f, Q = 0.f;
#pragma unroll
        for (int g = 0; g < 16; ++g) { S += sp[seg * 16 + g][ch]; Q += qp[seg * 16 + g][ch]; }
        sp2[seg][ch] = S; qp2[seg][ch] = Q;
    }
    __syncthreads();

    if (t < 16) {
        float S = 0.f, Q = 0.f;
#pragma unroll
        for (int g = 0; g < 16; ++g) { S += sp2[g][t]; Q += qp2[g][t]; }
        const float inv_n = 1.f / (float)(BB * NN);
        float mean = S * inv_n;
        float var  = Q * inv_n - mean * mean;
        float rstd = rsqrtf(var + BN_EPS);
        int cc = blockIdx.x * 16 + t;
        float g  = gamma[cc];
        float bt = beta[cc];
        scale[cc] = rstd * g;
        shift[cc] = bt - mean * rstd * g;
    }
}

// ---------------------------------------------------------------------------
// Kernel 4: apply normalization. float4 elementwise.
// ---------------------------------------------------------------------------
__global__ __launch_bounds__(256) void norm_kernel(
    const float* __restrict__ equ, const float* __restrict__ scale,
    const float* __restrict__ shift, float* __restrict__ out)
{
    const int idx = blockIdx.x * 256 + threadIdx.x;   // float4 index
    f4 e  = reinterpret_cast<const f4*>(equ)[idx];
    const int c4 = idx & 63;                          // channel quad
    f4 sc = reinterpret_cast<const f4*>(scale)[c4];
    f4 sh = reinterpret_cast<const f4*>(shift)[c4];
    f4 o;
#pragma unroll
    for (int k = 0; k < 4; ++k) o[k] = e[k] * sc[k] + sh[k];
    reinterpret_cast<f4*>(out)[idx] = o;
}

// ---------------------------------------------------------------------------
extern "C" void kernel_launch(void* const* d_in, const int* in_sizes, int n_in,
                              void* d_out, int out_size, void* d_ws, size_t ws_size,
                              hipStream_t stream) {
    (void)in_sizes; (void)n_in; (void)out_size; (void)ws_size;

    const float* nodes = (const float*)d_in[0];
    const float* edges = (const float*)d_in[1];
    const float* W1    = (const float*)d_in[2];
    const float* W2    = (const float*)d_in[3];
    const float* gamma = (const float*)d_in[4];
    const float* beta  = (const float*)d_in[5];
    float* out = (float*)d_out;

    const int nBN_H = BB * NN * HH;  // 262144
    float* ws    = (float*)d_ws;
    float* xleft = ws;
    float* xw2   = ws + nBN_H;
    float* equ   = ws + 2 * nBN_H;
    float* scale = ws + 3 * nBN_H;
    float* shift = ws + 3 * nBN_H + HH;

    proj_kernel<<<512, 256, 0, stream>>>(nodes, W1, W2, xleft, xw2);
    edge_kernel<<<512, 1024, 0, stream>>>(edges, xw2, xleft, equ);
    stats_kernel<<<16, 1024, 0, stream>>>(equ, gamma, beta, scale, shift);
    norm_kernel<<<256, 256, 0, stream>>>(equ, scale, shift, out);
}

// Round 5
// 71.370 us; speedup vs baseline: 1.4383x; 1.1819x over previous
//
#include <hip/hip_runtime.h>
#include <cstddef>

#define BB 4
#define NN 256
#define HH 256
#define BN_EPS 1e-5f
#define ETA_EPS 1e-20f

typedef float f4 __attribute__((ext_vector_type(4)));

__device__ __forceinline__ float fast_sigmoid(float x) {
    float ex = __expf(-x);
    return __builtin_amdgcn_rcpf(1.f + ex);
}

// ---------------------------------------------------------------------------
// Kernel 0: transpose W1,W2 -> WT1,WT2 (WT[h][o] = W[o][h]). 32 blocks.
// One-shot, ~1 MB traffic. Makes proj's W reads coalescible along o.
// ---------------------------------------------------------------------------
__global__ __launch_bounds__(256) void transpose_kernel(
    const float* __restrict__ W1, const float* __restrict__ W2,
    float* __restrict__ WT1, float* __restrict__ WT2)
{
    const int which = blockIdx.x >> 4;
    const int tile  = blockIdx.x & 15;
    const int tr = (tile >> 2) << 6, tc = (tile & 3) << 6;
    const float* __restrict__ W  = which ? W2 : W1;
    float* __restrict__ WT       = which ? WT2 : WT1;

    __shared__ float tl[64][65];
    const int c = threadIdx.x & 63, p0 = threadIdx.x >> 6;
#pragma unroll
    for (int p = 0; p < 16; ++p) {
        int r = p * 4 + p0;
        tl[c][r] = W[(tr + r) * HH + tc + c];     // coalesced read
    }
    __syncthreads();
#pragma unroll
    for (int p = 0; p < 16; ++p) {
        int cc = p * 4 + p0;
        WT[(tc + cc) * HH + tr + c] = tl[cc][c];  // coalesced write
    }
}

// ---------------------------------------------------------------------------
// Kernel 1: projections via WT.  out[r][o] = sum_h x[r][h] * WT[h][o].
// grid = 256 blocks: [0,128) -> WT1/xleft, [128,256) -> WT2/xw2.
// Block = 8 rows; thread (oq = t&63, hg = t>>6): lane=oq reads WT4[h][oq]
// -> 1 KB contiguous per wave-instr (the R4 version inflated L2 line
// traffic 8x with per-thread 16B strided row reads). x broadcast from LDS.
// ---------------------------------------------------------------------------
__global__ __launch_bounds__(256) void proj_kernel(
    const float* __restrict__ nodes, const float* __restrict__ WT1,
    const float* __restrict__ WT2, float* __restrict__ xleft,
    float* __restrict__ xw2)
{
    const int which = blockIdx.x >> 7;
    const int rb    = blockIdx.x & 127;   // 8-row group
    const float* __restrict__ WT = which ? WT2 : WT1;
    float* __restrict__ out      = which ? xw2 : xleft;
    const int t = threadIdx.x;

    __shared__ float xs[8][HH];           // 8 KB
    {
        f4* xs4 = reinterpret_cast<f4*>(xs);
        const f4* nodes4 = reinterpret_cast<const f4*>(nodes) + rb * 512;
#pragma unroll
        for (int m = 0; m < 2; ++m) xs4[m * 256 + t] = nodes4[m * 256 + t];
    }
    __syncthreads();

    const int oq = t & 63;                // f4 quad of output channels
    const int hg = t >> 6;                // h-group (wave id)
    const f4* __restrict__ WT4 = reinterpret_cast<const f4*>(WT);

    f4 acc[8];
#pragma unroll
    for (int r = 0; r < 8; ++r) acc[r] = (f4){0.f, 0.f, 0.f, 0.f};

    for (int hh = 0; hh < 64; ++hh) {
        const int h = hg * 64 + hh;
        f4 wv = WT4[h * 64 + oq];         // coalesced: 1 KB per wave
#pragma unroll
        for (int r = 0; r < 8; ++r)
            acc[r] += xs[r][h] * wv;      // xs broadcast (free)
    }

    __shared__ f4 ps[4][8][64];           // 32 KB, [hg][r][oq]: 2-way banks
#pragma unroll
    for (int r = 0; r < 8; ++r) ps[hg][r][oq] = acc[r];
    __syncthreads();

#pragma unroll
    for (int m = 0; m < 2; ++m) {
        int idx = m * 256 + t;            // 0..511 = 8 r x 64 oq
        int r = idx >> 6, o = idx & 63;
        f4 v = ps[0][r][o] + ps[1][r][o] + ps[2][r][o] + ps[3][r][o];
        reinterpret_cast<f4*>(out)[(rb * 8 + r) * 64 + o] = v;
    }
}

// ---------------------------------------------------------------------------
// Kernel 2: edge aggregation. Block = 8 i-rows x 64-ch slice x all j,
// 1024 threads, xw2 slice staged in LDS (64 KB, overlaid by reduction).
// Wave remap: wave w -> (il = w&7, jh = w>>3); lanes (jl = (t>>4)&3,
// q = t&15) read edges[i][j..j+4)[slice]: 4x256 B inside a 4 KB window
// (R4 had 4x256 B spread over 768 KB -> poor DRAM locality).
// ---------------------------------------------------------------------------
__global__ __launch_bounds__(1024) void edge_kernel(
    const float* __restrict__ edges, const float* __restrict__ xw2,
    const float* __restrict__ xleft, float* __restrict__ equ)
{
    const int blk = blockIdx.x;
    const int ig  = blk >> 2;
    const int hs4 = (blk & 3) * 16;
    const int bi0 = ig * 8;
    const int b   = bi0 >> 8;
    const int t   = threadIdx.x;

    __shared__ f4 xw_s[NN][16];        // 64 KB

    const f4* __restrict__ xw4 =
        reinterpret_cast<const f4*>(xw2) + (size_t)b * NN * 64;
#pragma unroll
    for (int m = 0; m < 4; ++m) {
        int idx = m * 1024 + t;
        int j = idx >> 4, q = idx & 15;
        xw_s[j][q] = xw4[j * 64 + hs4 + q];
    }
    __syncthreads();

    const int q  = t & 15;
    const int jl = (t >> 4) & 3;
    const int w  = t >> 6;
    const int il = w & 7;
    const int jh = w >> 3;

    const f4* __restrict__ erow =
        reinterpret_cast<const f4*>(edges) +
        ((size_t)(bi0 + il) * NN + jh * 128 + jl) * 64 + hs4 + q;

    float s0[4] = {0.f, 0.f, 0.f, 0.f};
    float s1[4] = {0.f, 0.f, 0.f, 0.f};

#pragma unroll 4
    for (int jj = 0; jj < 32; ++jj) {
        f4 e  = __builtin_nontemporal_load(erow + jj * 256);
        f4 xw = xw_s[jh * 128 + jj * 4 + jl][q];
#pragma unroll
        for (int k = 0; k < 4; ++k) {
            float sg = fast_sigmoid(e[k]);
            s0[k] += sg;
            s1[k] += sg * xw[k];
        }
    }
    __syncthreads();                   // xw_s dead; reuse for reduction

    float* red = reinterpret_cast<float*>(xw_s);
    {
        const int g = jh * 4 + jl;     // 8 j-partials
        f4* r0 = reinterpret_cast<f4*>(red) + (g * 8 + il) * 16 + q;
        f4* r1 = r0 + 1024;            // +4096 floats
        *r0 = (f4){s0[0], s0[1], s0[2], s0[3]};
        *r1 = (f4){s1[0], s1[1], s1[2], s1[3]};
    }
    __syncthreads();

    if (t < 512) {
        const int il2 = t >> 6;
        const int ch  = t & 63;
        float S0 = 0.f, S1 = 0.f;
#pragma unroll
        for (int g = 0; g < 8; ++g) {
            S0 += red[(g * 8 + il2) * 64 + ch];
            S1 += red[(g * 8 + il2) * 64 + ch + 4096];
        }
        const size_t off = (size_t)(bi0 + il2) * HH + hs4 * 4 + ch;
        equ[off] = xleft[off] + S1 / (S0 + ETA_EPS);
    }
}

// ---------------------------------------------------------------------------
// Kernel 3: BN batch stats. 16 blocks x 1024 threads (equ is only 1 MB).
// ---------------------------------------------------------------------------
__global__ __launch_bounds__(1024) void stats_kernel(
    const float* __restrict__ equ, const float* __restrict__ gamma,
    const float* __restrict__ beta, float* __restrict__ scale,
    float* __restrict__ shift)
{
    const int t     = threadIdx.x;
    const int ql    = t & 3;
    const int rg    = t >> 2;
    const int qbase = blockIdx.x * 4;

    const f4* __restrict__ equ4 = reinterpret_cast<const f4*>(equ);

    float s[4] = {0.f, 0.f, 0.f, 0.f};
    float qq[4] = {0.f, 0.f, 0.f, 0.f};
    for (int r = rg; r < BB * NN; r += 256) {
        f4 v = equ4[r * 64 + qbase + ql];
#pragma unroll
        for (int k = 0; k < 4; ++k) { s[k] += v[k]; qq[k] += v[k] * v[k]; }
    }

    __shared__ float sp[256][17];
    __shared__ float qp[256][17];
    __shared__ float sp2[16][17];
    __shared__ float qp2[16][17];
#pragma unroll
    for (int k = 0; k < 4; ++k) { sp[rg][ql * 4 + k] = s[k]; qp[rg][ql * 4 + k] = qq[k]; }
    __syncthreads();

    if (t < 256) {
        const int ch = t & 15, seg = t >> 4;
        float S = 0.f, Q = 0.f;
#pragma unroll
        for (int g = 0; g < 16; ++g) { S += sp[seg * 16 + g][ch]; Q += qp[seg * 16 + g][ch]; }
        sp2[seg][ch] = S; qp2[seg][ch] = Q;
    }
    __syncthreads();

    if (t < 16) {
        float S = 0.f, Q = 0.f;
#pragma unroll
        for (int g = 0; g < 16; ++g) { S += sp2[g][t]; Q += qp2[g][t]; }
        const float inv_n = 1.f / (float)(BB * NN);
        float mean = S * inv_n;
        float var  = Q * inv_n - mean * mean;
        float rstd = rsqrtf(var + BN_EPS);
        int cc = blockIdx.x * 16 + t;
        float g  = gamma[cc];
        float bt = beta[cc];
        scale[cc] = rstd * g;
        shift[cc] = bt - mean * rstd * g;
    }
}

// ---------------------------------------------------------------------------
// Kernel 4: apply normalization. float4 elementwise.
// ---------------------------------------------------------------------------
__global__ __launch_bounds__(256) void norm_kernel(
    const float* __restrict__ equ, const float* __restrict__ scale,
    const float* __restrict__ shift, float* __restrict__ out)
{
    const int idx = blockIdx.x * 256 + threadIdx.x;
    f4 e  = reinterpret_cast<const f4*>(equ)[idx];
    const int c4 = idx & 63;
    f4 sc = reinterpret_cast<const f4*>(scale)[c4];
    f4 sh = reinterpret_cast<const f4*>(shift)[c4];
    f4 o;
#pragma unroll
    for (int k = 0; k < 4; ++k) o[k] = e[k] * sc[k] + sh[k];
    reinterpret_cast<f4*>(out)[idx] = o;
}

// ---------------------------------------------------------------------------
extern "C" void kernel_launch(void* const* d_in, const int* in_sizes, int n_in,
                              void* d_out, int out_size, void* d_ws, size_t ws_size,
                              hipStream_t stream) {
    (void)in_sizes; (void)n_in; (void)out_size; (void)ws_size;

    const float* nodes = (const float*)d_in[0];
    const float* edges = (const float*)d_in[1];
    const float* W1    = (const float*)d_in[2];
    const float* W2    = (const float*)d_in[3];
    const float* gamma = (const float*)d_in[4];
    const float* beta  = (const float*)d_in[5];
    float* out = (float*)d_out;

    const int nBN_H = BB * NN * HH;  // 262144
    float* ws    = (float*)d_ws;
    float* xleft = ws;
    float* xw2   = ws + nBN_H;
    float* equ   = ws + 2 * nBN_H;
    float* scale = ws + 3 * nBN_H;
    float* shift = ws + 3 * nBN_H + 256;
    float* WT1   = ws + 3 * nBN_H + 512;
    float* WT2   = WT1 + HH * HH;

    transpose_kernel<<<32, 256, 0, stream>>>(W1, W2, WT1, WT2);
    proj_kernel<<<256, 256, 0, stream>>>(nodes, WT1, WT2, xleft, xw2);
    edge_kernel<<<512, 1024, 0, stream>>>(edges, xw2, xleft, equ);
    stats_kernel<<<16, 1024, 0, stream>>>(equ, gamma, beta, scale, shift);
    norm_kernel<<<256, 256, 0, stream>>>(equ, scale, shift, out);
}